// Round 6
// baseline (131.321 us; speedup 1.0000x reference)
//
#include <hip/hip_runtime.h>

#define BB 2
#define NN 2048
#define CQc 256
#define CHc 256
#define HHc 8
#define DDc 32

typedef __bf16 bf16_t;
typedef bf16_t bf16x8 __attribute__((ext_vector_type(8)));
typedef float f32x4 __attribute__((ext_vector_type(4)));

#define LOG2E 1.4426950408889634f

static __device__ __forceinline__ unsigned short f2bf(float f) {
  union { float f; unsigned u; } a; a.f = f;
  unsigned r = a.u + 0x7FFFu + ((a.u >> 16) & 1u);
  return (unsigned short)(r >> 16);
}

static __device__ __forceinline__ bf16x8 ldb8(const unsigned short* p) {
  return *reinterpret_cast<const bf16x8*>(p);
}

// ---------------- kernel 0: weights -> bf16, transposed [n][k] ----------------
__global__ void prep_w(const float* __restrict__ Wq, const float* __restrict__ Wk,
                       const float* __restrict__ Wv, const float* __restrict__ Wg,
                       const float* __restrict__ Wo, unsigned short* __restrict__ wt) {
  int gid = blockIdx.x * 256 + threadIdx.x;  // 0 .. 5*65536-1
  int w = gid >> 16, r = gid & 65535;
  int n = r >> 8, k = r & 255;
  const float* W = (w == 0) ? Wq : (w == 1) ? Wk : (w == 2) ? Wv : (w == 3) ? Wg : Wo;
  wt[gid] = f2bf(W[k * 256 + n]);
}

// ---------------- kernel 1: QKV + gate projections ----------------
// q is pre-scaled by (1/sqrt(D)) * log2(e) so attention softmax can use exp2.
__global__ __launch_bounds__(256) void proj_k(
    const float* __restrict__ X, const float* __restrict__ bq,
    const float* __restrict__ bg, const float* __restrict__ gbias,
    const unsigned short* __restrict__ wt,
    unsigned short* __restrict__ q_ws, unsigned short* __restrict__ k_ws,
    unsigned short* __restrict__ vt_ws, float* __restrict__ gate_ws) {
  const int tid = threadIdx.x;
  const int wave = tid >> 6, l = tid & 63, g = l >> 4, l15 = l & 15;
  const int mrow = blockIdx.x * 64 + wave * 16 + l15;  // A-fragment row
  const int c0 = blockIdx.y * 64;                      // global col in [0,1024)
  const int widx = c0 >> 8;                            // which weight
  const int nin0 = c0 & 255;                           // col within weight
  const unsigned short* W = wt + widx * 65536;

  f32x4 acc[4];
#pragma unroll
  for (int st = 0; st < 4; ++st) acc[st] = f32x4{0.f, 0.f, 0.f, 0.f};

#pragma unroll
  for (int kk0 = 0; kk0 < 256; kk0 += 32) {
    const float* xp = X + mrow * 256 + kk0 + 8 * g;
    f32x4 x0 = *reinterpret_cast<const f32x4*>(xp);
    f32x4 x1 = *reinterpret_cast<const f32x4*>(xp + 4);
    union { unsigned short u[8]; bf16x8 v; } av;
#pragma unroll
    for (int e = 0; e < 4; ++e) { av.u[e] = f2bf(x0[e]); av.u[4 + e] = f2bf(x1[e]); }
#pragma unroll
    for (int st = 0; st < 4; ++st) {
      bf16x8 bv = ldb8(W + (nin0 + st * 16 + l15) * 256 + kk0 + 8 * g);
      acc[st] = __builtin_amdgcn_mfma_f32_16x16x32_bf16(av.v, bv, acc[st], 0, 0, 0);
    }
  }

  const int mb = blockIdx.x * 64 + wave * 16 + 4 * g;  // D rows = 4g+j
#pragma unroll
  for (int st = 0; st < 4; ++st) {
    const int n = nin0 + st * 16 + l15;
#pragma unroll
    for (int j = 0; j < 4; ++j) {
      const int m = mb + j;
      const int b = m >> 11, t = m & 2047;
      float val = acc[st][j];
      if (widx == 0) {
        int h = n >> 5, d = n & 31;
        q_ws[((b * 8 + h) * 2048 + t) * 32 + d] =
            f2bf((val + bq[n]) * (0.17677669529663687f * LOG2E));
      } else if (widx == 1) {
        int h = n >> 5, d = n & 31;
        k_ws[((b * 8 + h) * 2048 + t) * 32 + d] = f2bf(val);
      } else if (widx == 2) {
        int h = n >> 5, d = n & 31;
        vt_ws[((b * 8 + h) * 32 + d) * 2048 + t] = f2bf(val);  // V transposed [b,h,d,n]
      } else {
        float z = val + bg[n] + gbias[n];
        gate_ws[m * 256 + n] = 1.0f / (1.0f + __expf(-z));
      }
    }
  }
}

// ---------------- kernel 2: flash attention, key-split waves, span-staged bias ----
// grid: 2048 blocks (16 bh * 128 q-tiles of 16 rows). 4 waves split the KEY dim:
// per 512-key span, wave w handles tiles {2w, 2w+1} (64 keys each) with private
// online-softmax state; 4-way exact merge at the end.
// Bias staged per span as [16 rows x 512 cols] fp32 into block-shared LDS (dbuf,
// pitch 516 floats): each global_load_lds reads 1 KB CONTIGUOUS from one bias row
// -> 8192 resident row-streams at 2 KB run length (vs 32768 @ 256 B in r5).
// Span-top: vmcnt(0) drains exactly stage(sp) (stage(sp+1) not yet issued), then
// raw s_barrier + sched_barrier(0). stage(sp+1) chunks issue AFTER each tile's
// K/V loads so compiler positional waits don't drain them.
__global__ __launch_bounds__(256) void attn_k(
    const unsigned short* __restrict__ q_ws, const unsigned short* __restrict__ k_ws,
    const unsigned short* __restrict__ vt_ws, const float* __restrict__ bias,
    unsigned short* __restrict__ o_ws) {
  __shared__ float sbias[2][16][516];           // 66 KB, pitch-padded
  __shared__ unsigned short plds[4 * 16 * 72];  // per-wave P buffer
  const int tid = threadIdx.x;
  const int wave = tid >> 6, l = tid & 63, g = l >> 4, l15 = l & 15;
  const int bh = blockIdx.x >> 7, qt = blockIdx.x & 127;
  const int qr0 = qt * 16;
  const int kvbase = bh * 2048;
  unsigned short* pw = plds + wave * (16 * 72);

  // all waves share the same 16 q-rows
  const bf16x8 qa = ldb8(q_ws + (size_t)(kvbase + qr0 + l15) * 32 + 8 * g);
  const unsigned short* kbase = k_ws + (size_t)kvbase * 32 + 8 * g + l15 * 32;
  const unsigned short* vbase = vt_ws + (size_t)(bh * 32 + l15) * 2048 + 8 * g;
  // staging source: wave w stages rows 4w..4w+3; per-lane 16B at lane*16
  const float* bias_base = bias + ((size_t)bh << 22) + (size_t)(qr0 + wave * 4) * 2048 + l * 4;

  // stage chunk c (rows 2c,2c+1 of this wave's 4) of span sp into buffer buf
#define STAGE(buf, sp, c)                                                          \
  {                                                                                \
    _Pragma("unroll") for (int rr = 2 * (c); rr < 2 * (c) + 2; ++rr)               \
        _Pragma("unroll") for (int h = 0; h < 2; ++h)                              \
            __builtin_amdgcn_global_load_lds(                                      \
                (const __attribute__((address_space(1))) void*)(                   \
                    bias_base + (size_t)rr * 2048 + (sp) * 512 + h * 256),         \
                (__attribute__((address_space(3))) void*)(                         \
                    &sbias[buf][wave * 4 + rr][h * 256]),                          \
                16, 0, 0);                                                         \
  }

  float mr[4], lr[4];
  f32x4 oacc[2];
#pragma unroll
  for (int j = 0; j < 4; ++j) { mr[j] = -1e30f; lr[j] = 0.0f; }
  oacc[0] = f32x4{0.f, 0.f, 0.f, 0.f};
  oacc[1] = f32x4{0.f, 0.f, 0.f, 0.f};

  // prologue: stage span 0 into buf 0
  STAGE(0, 0, 0);
  STAGE(0, 0, 1);

#pragma unroll 1
  for (int sp = 0; sp < 4; ++sp) {
    const int buf = sp & 1;
    // stage(sp) is the only outstanding vmem -> vmcnt(0) drains exactly it
    asm volatile("s_waitcnt vmcnt(0)" ::: "memory");
    __builtin_amdgcn_s_barrier();
    __builtin_amdgcn_sched_barrier(0);
#pragma unroll
    for (int t = 0; t < 2; ++t) {
      const int tile = 2 * wave + t;  // 0..7 within span
      const int k0 = sp * 512 + tile * 64;
      // K/V loads first (compiler positional waits then can't drain stage)
      bf16x8 kb[4];
#pragma unroll
      for (int st = 0; st < 4; ++st) kb[st] = ldb8(kbase + (size_t)(k0 + st * 16) * 32);
      bf16x8 vb[2][2];
#pragma unroll
      for (int dst = 0; dst < 2; ++dst)
#pragma unroll
        for (int kc = 0; kc < 2; ++kc)
          vb[dst][kc] = ldb8(vbase + (size_t)dst * 16 * 2048 + k0 + kc * 32);
      // stage chunk t of next span into the other buffer
      if (sp < 3) { STAGE(buf ^ 1, sp + 1, t); }
      // bias C-fragments from LDS span buffer
      f32x4 cfr[4];
#pragma unroll
      for (int st = 0; st < 4; ++st)
#pragma unroll
        for (int j = 0; j < 4; ++j)
          cfr[st][j] = sbias[buf][4 * g + j][tile * 64 + st * 16 + l15] * LOG2E;
      // S = QK^T + bias (C-operand), base-2 domain
      f32x4 s[4];
#pragma unroll
      for (int st = 0; st < 4; ++st)
        s[st] = __builtin_amdgcn_mfma_f32_16x16x32_bf16(qa, kb[st], cfr[st], 0, 0, 0);
      // online softmax per row (row = 4g+j)
#pragma unroll
      for (int j = 0; j < 4; ++j) {
        float mx = fmaxf(fmaxf(s[0][j], s[1][j]), fmaxf(s[2][j], s[3][j]));
        mx = fmaxf(mx, __shfl_xor(mx, 1));
        mx = fmaxf(mx, __shfl_xor(mx, 2));
        mx = fmaxf(mx, __shfl_xor(mx, 4));
        mx = fmaxf(mx, __shfl_xor(mx, 8));
        const float mn = fmaxf(mr[j], mx);
        const float sc = __builtin_amdgcn_exp2f(mr[j] - mn);
        mr[j] = mn;
        float rs = 0.f;
#pragma unroll
        for (int st = 0; st < 4; ++st) {
          float e = __builtin_amdgcn_exp2f(s[st][j] - mn);
          s[st][j] = e;
          rs += e;
        }
        rs += __shfl_xor(rs, 1);
        rs += __shfl_xor(rs, 2);
        rs += __shfl_xor(rs, 4);
        rs += __shfl_xor(rs, 8);
        lr[j] = lr[j] * sc + rs;
        oacc[0][j] *= sc;
        oacc[1][j] *= sc;
      }
      // P -> LDS transpose (per-wave buffer), then PV
#pragma unroll
      for (int st = 0; st < 4; ++st)
#pragma unroll
        for (int j = 0; j < 4; ++j)
          pw[(4 * g + j) * 72 + st * 16 + l15] = f2bf(s[st][j]);
#pragma unroll
      for (int kc = 0; kc < 2; ++kc) {
        bf16x8 pa = ldb8(pw + l15 * 72 + kc * 32 + 8 * g);
        oacc[0] = __builtin_amdgcn_mfma_f32_16x16x32_bf16(pa, vb[0][kc], oacc[0], 0, 0, 0);
        oacc[1] = __builtin_amdgcn_mfma_f32_16x16x32_bf16(pa, vb[1][kc], oacc[1], 0, 0, 0);
      }
    }
  }

  // ---- 4-way merge across waves (exact log-sum-exp combine) ----
  float* obuf = (float*)sbias;          // [4][16][32]
  float* mlbuf = obuf + 4 * 16 * 32;    // [4][16][2]
  __syncthreads();  // span reads done; safe to overlay
#pragma unroll
  for (int dst = 0; dst < 2; ++dst)
#pragma unroll
    for (int j = 0; j < 4; ++j)
      obuf[wave * 512 + (4 * g + j) * 32 + dst * 16 + l15] = oacc[dst][j];
  if (l15 == 0) {
#pragma unroll
    for (int j = 0; j < 4; ++j) {
      mlbuf[wave * 32 + (4 * g + j) * 2 + 0] = mr[j];
      mlbuf[wave * 32 + (4 * g + j) * 2 + 1] = lr[j];
    }
  }
  __syncthreads();
  if (wave == 0) {
    const int b = bh >> 3, h = bh & 7;
#pragma unroll
    for (int j = 0; j < 4; ++j) {
      const int r = 4 * g + j;
      float m0 = mlbuf[r * 2], m1 = mlbuf[32 + r * 2];
      float m2 = mlbuf[64 + r * 2], m3 = mlbuf[96 + r * 2];
      const float ms = fmaxf(fmaxf(m0, m1), fmaxf(m2, m3));
      const float w0 = __builtin_amdgcn_exp2f(m0 - ms);
      const float w1 = __builtin_amdgcn_exp2f(m1 - ms);
      const float w2 = __builtin_amdgcn_exp2f(m2 - ms);
      const float w3 = __builtin_amdgcn_exp2f(m3 - ms);
      const float den = mlbuf[r * 2 + 1] * w0 + mlbuf[32 + r * 2 + 1] * w1 +
                        mlbuf[64 + r * 2 + 1] * w2 + mlbuf[96 + r * 2 + 1] * w3;
      const int q = qr0 + r;
#pragma unroll
      for (int dst = 0; dst < 2; ++dst) {
        const int c = dst * 16 + l15;
        const float num = obuf[r * 32 + c] * w0 + obuf[512 + r * 32 + c] * w1 +
                          obuf[1024 + r * 32 + c] * w2 + obuf[1536 + r * 32 + c] * w3;
        o_ws[((size_t)(b * 2048 + q)) * 256 + h * 32 + c] = f2bf(num / den);
      }
    }
  }
#undef STAGE
}

// ---------------- kernel 3: out = gate * (o @ Wout + bout) ----------------
__global__ __launch_bounds__(256) void outp_k(
    const unsigned short* __restrict__ o_ws, const unsigned short* __restrict__ wot,
    const float* __restrict__ bout, const float* __restrict__ gate_ws,
    float* __restrict__ out) {
  const int tid = threadIdx.x;
  const int wave = tid >> 6, l = tid & 63, g = l >> 4, l15 = l & 15;
  const int m0 = blockIdx.x * 64 + wave * 16;
  const int c0 = blockIdx.y * 64;
  f32x4 acc[4];
#pragma unroll
  for (int st = 0; st < 4; ++st) acc[st] = f32x4{0.f, 0.f, 0.f, 0.f};
#pragma unroll
  for (int kk0 = 0; kk0 < 256; kk0 += 32) {
    bf16x8 a = ldb8(o_ws + (m0 + l15) * 256 + kk0 + 8 * g);
#pragma unroll
    for (int st = 0; st < 4; ++st) {
      bf16x8 bv = ldb8(wot + (c0 + st * 16 + l15) * 256 + kk0 + 8 * g);
      acc[st] = __builtin_amdgcn_mfma_f32_16x16x32_bf16(a, bv, acc[st], 0, 0, 0);
    }
  }
  const int mb = m0 + 4 * g;
#pragma unroll
  for (int st = 0; st < 4; ++st) {
    const int n = c0 + st * 16 + l15;
#pragma unroll
    for (int j = 0; j < 4; ++j) {
      const int m = mb + j;
      const float val = acc[st][j] + bout[n];
      out[m * 256 + n] = gate_ws[m * 256 + n] * val;
    }
  }
}

extern "C" void kernel_launch(void* const* d_in, const int* in_sizes, int n_in,
                              void* d_out, int out_size, void* d_ws, size_t ws_size,
                              hipStream_t stream) {
  const float* q_x   = (const float*)d_in[0];
  const float* bias  = (const float*)d_in[1];
  const float* Wq    = (const float*)d_in[2];
  const float* bq    = (const float*)d_in[3];
  const float* Wk    = (const float*)d_in[4];
  const float* Wv    = (const float*)d_in[5];
  const float* Wout  = (const float*)d_in[6];
  const float* bout  = (const float*)d_in[7];
  const float* Wg    = (const float*)d_in[8];
  const float* bg    = (const float*)d_in[9];
  const float* gbias = (const float*)d_in[10];
  float* out = (float*)d_out;

  char* ws = (char*)d_ws;
  unsigned short* wt    = (unsigned short*)(ws);                        // 655,360 B
  unsigned short* q_ws  = (unsigned short*)(ws + 655360);               // 2 MB
  unsigned short* k_ws  = (unsigned short*)(ws + 655360 + 2097152);     // 2 MB
  unsigned short* vt_ws = (unsigned short*)(ws + 655360 + 2 * 2097152); // 2 MB
  unsigned short* o_ws  = (unsigned short*)(ws + 655360 + 3 * 2097152); // 2 MB
  float* gate_ws        = (float*)(ws + 655360 + 4 * 2097152);          // 4 MB

  prep_w<<<1280, 256, 0, stream>>>(Wq, Wk, Wv, Wg, Wout, wt);
  proj_k<<<dim3(64, 16), 256, 0, stream>>>(q_x, bq, bg, gbias, wt, q_ws, k_ws, vt_ws, gate_ws);
  attn_k<<<2048, 256, 0, stream>>>(q_ws, k_ws, vt_ws, bias, o_ws);
  outp_k<<<dim3(64, 4), 256, 0, stream>>>(o_ws, wt + 4 * 65536, bout, gate_ws, out);
}